// Round 7
// baseline (1183.318 us; speedup 1.0000x reference)
//
#include <hip/hip_runtime.h>

#define NTHREADS 256
#define KDIM 5
#define CHUNK_M 256
#define CHUNK_FLOATS (CHUNK_M * KDIM)   // 1280 floats = 5 KB per stack
#define NCHUNK (4096 / CHUNK_M)         // 16
#define NBUF 2

#define WAITV(n) asm volatile("s_waitcnt vmcnt(" #n ")" ::: "memory")

typedef float __attribute__((address_space(3))) lds_f;
typedef const float __attribute__((address_space(1))) glb_f;

// out[n,g] = act( sum_{m,k,f} Ld[n,m,k]*v[m,f]*P[f,g,k] + Lu[n,m,k]*v[m,f]*Q[f,g,k] )
// Block handles one output row. Stacks stream through a 2-buffer LDS pipeline
// via global_load_lds (4 loads/chunk/wave, widths 16/4); v rides in a register
// double-buffer (plain dword loads from L2-resident 48 KB array), issued
// BEFORE stage(c+2) so WAITV(4) at the next chunk top drains it together with
// stage(c+1). LDS 20.5 KB -> 7 blocks/CU = 28 waves. REV = boustrophedon for
// cross-pass L3 reuse.
template <int FIN, int FOUT, bool ACT, bool REV>
__global__ __launch_bounds__(NTHREADS, 7)
void sc_pass(const float* __restrict__ Ld, const float* __restrict__ Lu,
             const float* __restrict__ v,   // [N, FIN]
             const float* __restrict__ P,   // [FIN, FOUT, K]
             const float* __restrict__ Q,   // [FIN, FOUT, K]
             float* __restrict__ out)       // [N, FOUT]
{
    constexpr int N = 4096;
    constexpr int NA = KDIM * FIN;

    __shared__ float sLd[NBUF][CHUNK_FLOATS];   // 10 KB
    __shared__ float sLu[NBUF][CHUNK_FLOATS];   // 10 KB
    __shared__ float red[NTHREADS / 64][2 * NA];

    const int n    = REV ? (N - 1 - blockIdx.x) : blockIdx.x;
    const int tid  = threadIdx.x;
    const int wid  = tid >> 6;
    const int lane = tid & 63;

    const float* __restrict__ ldrow = Ld + (size_t)n * N * KDIM;
    const float* __restrict__ lurow = Lu + (size_t)n * N * KDIM;

    // Stage chunk c into buffer b: 4 global_load_lds per wave. Wave wid owns
    // floats [wid*320 .. wid*320+319] of each 1280-float chunk: one width-16
    // (lane*16B) + one width-4 (lane*4B). LDS dest wave-uniform (+lane*width).
    auto stage = [&](int c, int b) {
        const size_t cbase = (size_t)c * CHUNK_FLOATS;
        const int wf = wid * 320;
        __builtin_amdgcn_global_load_lds((glb_f*)(ldrow + cbase + wf + lane * 4),
                                         (lds_f*)&sLd[b][wf], 16, 0, 0);
        __builtin_amdgcn_global_load_lds((glb_f*)(ldrow + cbase + wf + 256 + lane),
                                         (lds_f*)&sLd[b][wf + 256], 4, 0, 0);
        __builtin_amdgcn_global_load_lds((glb_f*)(lurow + cbase + wf + lane * 4),
                                         (lds_f*)&sLu[b][wf], 16, 0, 0);
        __builtin_amdgcn_global_load_lds((glb_f*)(lurow + cbase + wf + 256 + lane),
                                         (lds_f*)&sLu[b][wf + 256], 4, 0, 0);
    };

    float accd[NA], accu[NA];
#pragma unroll
    for (int j = 0; j < NA; ++j) { accd[j] = 0.f; accu[j] = 0.f; }

    // v register double-buffer: svn holds chunk c's values at iter-c top.
    float svn[FIN];
#pragma unroll
    for (int f = 0; f < FIN; ++f) svn[f] = v[(size_t)tid * FIN + f];

    stage(0, 0);
    stage(1, 1);   // 8 stack loads outstanding per wave (+1 tracked v load)

    for (int c = 0; c < NCHUNK; ++c) {
        // Drain stage(c) (and the compiler-tracked v load issued before
        // stage(c+1)); keep stage(c+1)'s 4 loads in flight.
        if (c + 1 < NCHUNK) WAITV(4); else WAITV(0);
        __builtin_amdgcn_s_barrier();    // all waves' chunk-c data in LDS

        const int b = c & 1;

        float sv[FIN];
#pragma unroll
        for (int f = 0; f < FIN; ++f) sv[f] = svn[f];

        // Prefetch v for chunk c+1 NOW (before stage(c+2)) so the next
        // WAITV(4) covers it.
        if (c + 1 < NCHUNK) {
            const int m1 = (c + 1) * CHUNK_M + tid;
#pragma unroll
            for (int f = 0; f < FIN; ++f) svn[f] = v[(size_t)m1 * FIN + f];
        }

        // stride 5 coprime with 32 banks -> 2 lanes/bank -> conflict-free.
        float ldv[KDIM], luv[KDIM];
#pragma unroll
        for (int q = 0; q < KDIM; ++q) {
            ldv[q] = sLd[b][tid * KDIM + q];
            luv[q] = sLu[b][tid * KDIM + q];
        }
#pragma unroll
        for (int k = 0; k < KDIM; ++k)
#pragma unroll
            for (int f = 0; f < FIN; ++f) {
                accd[k * FIN + f] += ldv[k] * sv[f];
                accu[k * FIN + f] += luv[k] * sv[f];
            }

        asm volatile("" ::: "memory");   // pin this chunk's LDS reads
        __builtin_amdgcn_s_barrier();    // all waves done reading buf b
        if (c + 2 < NCHUNK) stage(c + 2, b);   // overwrite buf just read: safe
    }

    // ---- block reduction: 2*NA scalars ----
#pragma unroll
    for (int j = 0; j < NA; ++j) {
        float vd = accd[j], vu = accu[j];
#pragma unroll
        for (int off = 32; off > 0; off >>= 1) {
            vd += __shfl_xor(vd, off);
            vu += __shfl_xor(vu, off);
        }
        if (lane == 0) { red[wid][j] = vd; red[wid][NA + j] = vu; }
    }
    __syncthreads();

    if (tid == 0) {
        float h[FOUT];
#pragma unroll
        for (int g = 0; g < FOUT; ++g) h[g] = 0.f;
#pragma unroll
        for (int k = 0; k < KDIM; ++k)
#pragma unroll
            for (int f = 0; f < FIN; ++f) {
                float td = 0.f, tu = 0.f;
#pragma unroll
                for (int w = 0; w < NTHREADS / 64; ++w) {
                    td += red[w][k * FIN + f];
                    tu += red[w][NA + k * FIN + f];
                }
#pragma unroll
                for (int g = 0; g < FOUT; ++g) {
                    h[g] += td * P[(f * FOUT + g) * KDIM + k]
                          + tu * Q[(f * FOUT + g) * KDIM + k];
                }
            }
#pragma unroll
        for (int g = 0; g < FOUT; ++g) {
            float hv = h[g];
            out[(size_t)n * FOUT + g] = ACT ? (hv >= 0.f ? hv : 0.01f * hv) : hv;
        }
    }
}

extern "C" void kernel_launch(void* const* d_in, const int* in_sizes, int n_in,
                              void* d_out, int out_size, void* d_ws, size_t ws_size,
                              hipStream_t stream) {
    constexpr int N = 4096;
    const float* Ld = (const float*)d_in[0];
    const float* Lu = (const float*)d_in[1];
    const float* x  = (const float*)d_in[2];
    const float* P1 = (const float*)d_in[3];
    const float* Q1 = (const float*)d_in[4];
    const float* P2 = (const float*)d_in[5];
    const float* Q2 = (const float*)d_in[6];
    const float* P3 = (const float*)d_in[7];
    const float* Q3 = (const float*)d_in[8];
    float* out = (float*)d_out;

    float* s1 = (float*)d_ws;          // sigma(h1): [N,3]
    float* s2 = s1 + (size_t)N * 3;    // sigma(h2): [N,3]

    // Boustrophedon: pass 2 reversed so it starts on rows pass 1 just
    // finished (L3-hot); pass 3 forward for the same reason vs pass 2.
    sc_pass<1, 3, true , false><<<N, NTHREADS, 0, stream>>>(Ld, Lu, x,  P1, Q1, s1);
    sc_pass<3, 3, true , true ><<<N, NTHREADS, 0, stream>>>(Ld, Lu, s1, P2, Q2, s2);
    sc_pass<3, 1, false, false><<<N, NTHREADS, 0, stream>>>(Ld, Lu, s2, P3, Q3, out);
}

// Round 8
// 351.327 us; speedup vs baseline: 3.3681x; 3.3681x over previous
//
#include <hip/hip_runtime.h>

#define NTHREADS 256
#define KDIM 5
#define CHUNK_M 256
#define CHUNK_FLOATS (CHUNK_M * KDIM)   // 1280 floats = 5 KB per stack
#define NCHUNK (4096 / CHUNK_M)         // 16
#define NBUF 2

#define WAITV(n) asm volatile("s_waitcnt vmcnt(" #n ")" ::: "memory")

typedef float __attribute__((address_space(3))) lds_f;
typedef const float __attribute__((address_space(1))) glb_f;

// out[n,g] = act( sum_{m,k,f} Ld[n,m,k]*v[m,f]*P[f,g,k] + Lu[n,m,k]*v[m,f]*Q[f,g,k] )
// Block handles one output row. Stacks stream through a 2-buffer LDS pipeline
// via global_load_lds (4 loads/chunk/wave, widths 16/4); v rides in a register
// double-buffer (plain dword loads from L2-resident 48 KB array), issued
// BEFORE stage(c+2) so WAITV(4) at the next chunk top drains it together with
// stage(c+1). LDS 20.5 KB -> 7 blocks/CU = 28 waves (LDS-limited, NOT
// launch_bounds-limited: a min-waves/EU=7 bound capped VGPR at 36 and spilled
// 840 MB/pass to scratch in R7 — never cap registers on this kernel).
template <int FIN, int FOUT, bool ACT, bool REV>
__global__ __launch_bounds__(NTHREADS)
void sc_pass(const float* __restrict__ Ld, const float* __restrict__ Lu,
             const float* __restrict__ v,   // [N, FIN]
             const float* __restrict__ P,   // [FIN, FOUT, K]
             const float* __restrict__ Q,   // [FIN, FOUT, K]
             float* __restrict__ out)       // [N, FOUT]
{
    constexpr int N = 4096;
    constexpr int NA = KDIM * FIN;

    __shared__ float sLd[NBUF][CHUNK_FLOATS];   // 10 KB
    __shared__ float sLu[NBUF][CHUNK_FLOATS];   // 10 KB
    __shared__ float red[NTHREADS / 64][2 * NA];

    const int n    = REV ? (N - 1 - blockIdx.x) : blockIdx.x;
    const int tid  = threadIdx.x;
    const int wid  = tid >> 6;
    const int lane = tid & 63;

    const float* __restrict__ ldrow = Ld + (size_t)n * N * KDIM;
    const float* __restrict__ lurow = Lu + (size_t)n * N * KDIM;

    // Stage chunk c into buffer b: 4 global_load_lds per wave. Wave wid owns
    // floats [wid*320 .. wid*320+319] of each 1280-float chunk: one width-16
    // (lane*16B) + one width-4 (lane*4B). LDS dest wave-uniform (+lane*width).
    auto stage = [&](int c, int b) {
        const size_t cbase = (size_t)c * CHUNK_FLOATS;
        const int wf = wid * 320;
        __builtin_amdgcn_global_load_lds((glb_f*)(ldrow + cbase + wf + lane * 4),
                                         (lds_f*)&sLd[b][wf], 16, 0, 0);
        __builtin_amdgcn_global_load_lds((glb_f*)(ldrow + cbase + wf + 256 + lane),
                                         (lds_f*)&sLd[b][wf + 256], 4, 0, 0);
        __builtin_amdgcn_global_load_lds((glb_f*)(lurow + cbase + wf + lane * 4),
                                         (lds_f*)&sLu[b][wf], 16, 0, 0);
        __builtin_amdgcn_global_load_lds((glb_f*)(lurow + cbase + wf + 256 + lane),
                                         (lds_f*)&sLu[b][wf + 256], 4, 0, 0);
    };

    float accd[NA], accu[NA];
#pragma unroll
    for (int j = 0; j < NA; ++j) { accd[j] = 0.f; accu[j] = 0.f; }

    // v register double-buffer: svn holds chunk c's values at iter-c top.
    float svn[FIN];
#pragma unroll
    for (int f = 0; f < FIN; ++f) svn[f] = v[(size_t)tid * FIN + f];

    stage(0, 0);
    stage(1, 1);   // 8 stack loads outstanding per wave (+1 tracked v load)

    for (int c = 0; c < NCHUNK; ++c) {
        // Drain stage(c) (and the compiler-tracked v load issued before
        // stage(c+1)); keep stage(c+1)'s 4 loads in flight.
        if (c + 1 < NCHUNK) WAITV(4); else WAITV(0);
        __builtin_amdgcn_s_barrier();    // all waves' chunk-c data in LDS

        const int b = c & 1;

        float sv[FIN];
#pragma unroll
        for (int f = 0; f < FIN; ++f) sv[f] = svn[f];

        // Prefetch v for chunk c+1 NOW (before stage(c+2)) so the next
        // WAITV(4) covers it.
        if (c + 1 < NCHUNK) {
            const int m1 = (c + 1) * CHUNK_M + tid;
#pragma unroll
            for (int f = 0; f < FIN; ++f) svn[f] = v[(size_t)m1 * FIN + f];
        }

        // stride 5 coprime with 32 banks -> 2 lanes/bank -> conflict-free.
        float ldv[KDIM], luv[KDIM];
#pragma unroll
        for (int q = 0; q < KDIM; ++q) {
            ldv[q] = sLd[b][tid * KDIM + q];
            luv[q] = sLu[b][tid * KDIM + q];
        }
#pragma unroll
        for (int k = 0; k < KDIM; ++k)
#pragma unroll
            for (int f = 0; f < FIN; ++f) {
                accd[k * FIN + f] += ldv[k] * sv[f];
                accu[k * FIN + f] += luv[k] * sv[f];
            }

        asm volatile("" ::: "memory");   // pin this chunk's LDS reads
        __builtin_amdgcn_s_barrier();    // all waves done reading buf b
        if (c + 2 < NCHUNK) stage(c + 2, b);   // overwrite buf just read: safe
    }

    // ---- block reduction: 2*NA scalars ----
#pragma unroll
    for (int j = 0; j < NA; ++j) {
        float vd = accd[j], vu = accu[j];
#pragma unroll
        for (int off = 32; off > 0; off >>= 1) {
            vd += __shfl_xor(vd, off);
            vu += __shfl_xor(vu, off);
        }
        if (lane == 0) { red[wid][j] = vd; red[wid][NA + j] = vu; }
    }
    __syncthreads();

    if (tid == 0) {
        float h[FOUT];
#pragma unroll
        for (int g = 0; g < FOUT; ++g) h[g] = 0.f;
#pragma unroll
        for (int k = 0; k < KDIM; ++k)
#pragma unroll
            for (int f = 0; f < FIN; ++f) {
                float td = 0.f, tu = 0.f;
#pragma unroll
                for (int w = 0; w < NTHREADS / 64; ++w) {
                    td += red[w][k * FIN + f];
                    tu += red[w][NA + k * FIN + f];
                }
#pragma unroll
                for (int g = 0; g < FOUT; ++g) {
                    h[g] += td * P[(f * FOUT + g) * KDIM + k]
                          + tu * Q[(f * FOUT + g) * KDIM + k];
                }
            }
#pragma unroll
        for (int g = 0; g < FOUT; ++g) {
            float hv = h[g];
            out[(size_t)n * FOUT + g] = ACT ? (hv >= 0.f ? hv : 0.01f * hv) : hv;
        }
    }
}

extern "C" void kernel_launch(void* const* d_in, const int* in_sizes, int n_in,
                              void* d_out, int out_size, void* d_ws, size_t ws_size,
                              hipStream_t stream) {
    constexpr int N = 4096;
    const float* Ld = (const float*)d_in[0];
    const float* Lu = (const float*)d_in[1];
    const float* x  = (const float*)d_in[2];
    const float* P1 = (const float*)d_in[3];
    const float* Q1 = (const float*)d_in[4];
    const float* P2 = (const float*)d_in[5];
    const float* Q2 = (const float*)d_in[6];
    const float* P3 = (const float*)d_in[7];
    const float* Q3 = (const float*)d_in[8];
    float* out = (float*)d_out;

    float* s1 = (float*)d_ws;          // sigma(h1): [N,3]
    float* s2 = s1 + (size_t)N * 3;    // sigma(h2): [N,3]

    // Boustrophedon: pass 2 reversed so it starts on rows pass 1 just
    // finished (L3-hot); pass 3 forward for the same reason vs pass 2.
    sc_pass<1, 3, true , false><<<N, NTHREADS, 0, stream>>>(Ld, Lu, x,  P1, Q1, s1);
    sc_pass<3, 3, true , true ><<<N, NTHREADS, 0, stream>>>(Ld, Lu, s1, P2, Q2, s2);
    sc_pass<3, 1, false, false><<<N, NTHREADS, 0, stream>>>(Ld, Lu, s2, P3, Q3, out);
}